// Round 8
// baseline (303.817 us; speedup 1.0000x reference)
//
#include <hip/hip_runtime.h>
#include <hip/hip_bf16.h>

#define TOKS 16384
#define HID  4096
#define NEXP 64
#define EPS  1e-4f   // flag threshold; bf16-split logit err ~3e-6 -> 30x margin

// ===== ws layout (floats) =====
// [0..63] prob sums | [64..127] argmax counts | int@[128] flag count |
// ints [192..192+16384) flag list | [16576) Bpack (1 MB, bf16 hi/lo frag-packed)
#define WS_FLAGCNT  128
#define WS_FLAGLIST 192
#define WS_BPACK    16576
#define BPK_LO      262144   // ushort offset of lo plane inside Bpack

typedef __attribute__((ext_vector_type(8))) short short8_t;
typedef __attribute__((ext_vector_type(4))) float f32x4;

static __device__ __forceinline__ unsigned short f2bf_rn(float x) {
    unsigned u = __builtin_bit_cast(unsigned, x);
    u = (u + 0x7fffu + ((u >> 16) & 1u)) >> 16;
    return (unsigned short)u;
}
static __device__ __forceinline__ float bf2f(unsigned short h) {
    return __builtin_bit_cast(float, (unsigned)h << 16);
}

// ---------- prep: W -> frag-ready bf16 hi/lo pack; zero reduction slots ----------
// Bpack[kt 0..127][nt 0..3][lane 0..63][j 0..7] = Wsplit[n=nt*16+(lane&15)][k=kt*32+8*(lane>>4)+j]
__global__ void moe_prep(const float* __restrict__ W, unsigned short* __restrict__ Bpk,
                         float* __restrict__ wsf) {
    const int idx = blockIdx.x * blockDim.x + threadIdx.x;
    if (idx < 192) wsf[idx] = 0.0f;
    if (idx >= NEXP * HID) return;
    const int n = idx >> 12;
    const int k = idx & 4095;
    const float w = W[idx];
    const unsigned short hi = f2bf_rn(w);
    const unsigned short lo = f2bf_rn(w - bf2f(hi));
    const int kt   = k >> 5;
    const int nt   = n >> 4;
    const int lane = (n & 15) | (((k >> 3) & 3) << 4);
    const int j    = k & 7;
    const int dst  = (((kt << 2) + nt) << 9) + (lane << 3) + j;
    Bpk[dst]          = hi;
    Bpk[BPK_LO + dst] = lo;
}

// ---------- fused: register-direct MFMA GEMM + softmax + bitonic top-8 + flag ----------
// 512 thr = 8 waves; 16 tokens/block; wave w owns K-eighth (512 k = 16 kt steps).
// A-frags straight from global (lane's 32 B contiguous in k): no LDS/barriers in GEMM.
// 4 blocks/CU * 8 waves = 32 waves/CU (HW max) -> TLP hides the serial load chains.
__global__ __launch_bounds__(512, 8)
void moe_fused(const float* __restrict__ X, const unsigned short* __restrict__ Bpk,
               float* __restrict__ out, float* __restrict__ wsf) {
    __shared__ __align__(16) float L[8][16][68];   // [kq][tok][exp(+pad)] = 34816 B

    const int tid  = threadIdx.x;
    const int lane = tid & 63;
    const int w    = tid >> 6;            // K-eighth 0..7
    const int tok0 = blockIdx.x * 16;

    const int mrow = lane & 15;           // token within tile (= A row)
    const int g    = lane >> 4;           // k-subgroup 0..3
    const size_t xbase = (size_t)(tok0 + mrow) * HID + ((size_t)w << 9) + (g << 3);
    const unsigned short* bb0 = Bpk + (((size_t)w << 4) << 11) + (lane << 3);

    f32x4 acc[4];
    #pragma unroll
    for (int nt = 0; nt < 4; ++nt) acc[nt] = (f32x4){0.f, 0.f, 0.f, 0.f};

    float4 nxa = *(const float4*)&X[xbase];
    float4 nxb = *(const float4*)&X[xbase + 4];

    #pragma unroll 2
    for (int c = 0; c < 16; ++c) {
        const float4 xa = nxa, xb = nxb;
        if (c < 15) {
            nxa = *(const float4*)&X[xbase + ((c + 1) << 5)];
            nxb = *(const float4*)&X[xbase + ((c + 1) << 5) + 4];
        }
        const float xv[8] = {xa.x, xa.y, xa.z, xa.w, xb.x, xb.y, xb.z, xb.w};
        short8_t ah, al;
        #pragma unroll
        for (int j = 0; j < 8; ++j) {
            const unsigned short h = f2bf_rn(xv[j]);
            ah[j] = (short)h;
            al[j] = (short)f2bf_rn(xv[j] - bf2f(h));
        }
        const unsigned short* bb = bb0 + ((size_t)c << 11);
        #pragma unroll
        for (int nt = 0; nt < 4; ++nt) {
            const short8_t bh = *(const short8_t*)(bb + (nt << 9));
            const short8_t bl = *(const short8_t*)(bb + BPK_LO + (nt << 9));
            acc[nt] = __builtin_amdgcn_mfma_f32_16x16x32_bf16(ah, bh, acc[nt], 0, 0, 0);
            acc[nt] = __builtin_amdgcn_mfma_f32_16x16x32_bf16(al, bh, acc[nt], 0, 0, 0);
            acc[nt] = __builtin_amdgcn_mfma_f32_16x16x32_bf16(ah, bl, acc[nt], 0, 0, 0);
        }
    }

    // C/D: col=lane&15 -> expert within ntile, row=(lane>>4)*4+r -> token
    #pragma unroll
    for (int nt = 0; nt < 4; ++nt)
        #pragma unroll
        for (int r = 0; r < 4; ++r)
            L[w][(g << 2) + r][(nt << 4) + mrow] = acc[nt][r];
    __syncthreads();

    // epilogue: wave w handles tokens w*2 .. w*2+1; lane = expert
    float* outIdx = out;
    float* outW   = out + TOKS * 8;
    int* flagcnt  = (int*)wsf + WS_FLAGCNT;
    int* flaglist = (int*)wsf + WS_FLAGLIST;

    float rp = 0.f;
    #pragma unroll
    for (int tt = 0; tt < 2; ++tt) {
        const int tl = (w << 1) + tt;
        const float lg = ((L[0][tl][lane] + L[1][tl][lane]) + (L[2][tl][lane] + L[3][tl][lane]))
                       + ((L[4][tl][lane] + L[5][tl][lane]) + (L[6][tl][lane] + L[7][tl][lane]));

        // bitonic sort-64, descending by (value, then lower index first)
        float v = lg; int idx = lane;
        #pragma unroll
        for (int size = 2; size <= 64; size <<= 1) {
            #pragma unroll
            for (int str = size >> 1; str > 0; str >>= 1) {
                const float ov = __shfl_xor(v, str, 64);
                const int   oi = __shfl_xor(idx, str, 64);
                const bool pb = (ov > v) || (ov == v && oi < idx);      // partner ranks first
                const bool keepFirst = ((lane & str) == 0) == ((lane & size) == 0);
                if (pb == keepFirst) { v = ov; idx = oi; }
            }
        }

        const float m = __shfl(v, 0, 64);          // max logit
        const float p = __expf(lg - m);
        float s = p;
        #pragma unroll
        for (int o = 32; o; o >>= 1) s += __shfl_xor(s, o, 64);
        const float inv_s = 1.0f / s;
        rp += p * inv_s;

        const float wkv = __expf(v - m) * inv_s;   // my rank's score
        float d8 = (lane < 8) ? wkv : 0.f;
        #pragma unroll
        for (int o = 1; o < 8; o <<= 1) d8 += __shfl_xor(d8, o, 64);
        const float invd = 1.0f / (d8 + 1e-20f);
        const float nv = __shfl_down(v, 1, 64);
        const bool flg = __any(lane < 8 && (v - nv) < EPS);

        const int gtok = tok0 + tl;
        if (lane < 8) {
            outIdx[(size_t)gtok * 8 + lane] = (float)idx;
            outW[(size_t)gtok * 8 + lane]   = wkv * invd;
        }
        if (lane == 0) {
            atomicAdd(&wsf[NEXP + idx], 1.0f);     // argmax histogram
            if (flg) {
                const int pos = atomicAdd(flagcnt, 1);
                if (pos < TOKS) flaglist[pos] = gtok;
            }
        }
    }
    atomicAdd(&wsf[lane], rp);
}

// ---------- exact fp64 redo for flagged tokens ----------
__global__ __launch_bounds__(256, 2)
void moe_fix(const float* __restrict__ X, const float* __restrict__ W,
             float* __restrict__ out, float* __restrict__ wsf) {
    __shared__ double red[256];
    const int tid = threadIdx.x;
    const int e   = tid & 63;
    const int kc  = tid >> 6;
    const int nf  = min(*((int*)wsf + WS_FLAGCNT), TOKS);
    const int* flaglist = (const int*)wsf + WS_FLAGLIST;
    float* outIdx = out;
    float* outW   = out + TOKS * 8;

    for (int fi = blockIdx.x; fi < nf; fi += gridDim.x) {
        const int tok = flaglist[fi];
        const float* xrow = X + (size_t)tok * HID + kc * 1024;
        const float* wrow = W + (size_t)e  * HID + kc * 1024;
        double part = 0.0;
        for (int j = 0; j < 1024; j += 4) {
            const float4 xv = *(const float4*)(xrow + j);
            const float4 wv = *(const float4*)(wrow + j);
            part = fma((double)xv.x, (double)wv.x, part);
            part = fma((double)xv.y, (double)wv.y, part);
            part = fma((double)xv.z, (double)wv.z, part);
            part = fma((double)xv.w, (double)wv.w, part);
        }
        red[tid] = part;
        __syncthreads();
        if (tid < 64) {
            const double lg = ((red[tid] + red[64 + tid]) + red[128 + tid]) + red[192 + tid];
            const float lgf = (float)lg;
            float m = lgf;
            #pragma unroll
            for (int o = 32; o; o >>= 1) m = fmaxf(m, __shfl_xor(m, o, 64));
            const float p = __expf(lgf - m);
            float s = p;
            #pragma unroll
            for (int o = 32; o; o >>= 1) s += __shfl_xor(s, o, 64);
            const float inv_s = 1.0f / s;

            double v = lg;
            double bw[8]; int ik[8];
            #pragma unroll
            for (int k = 0; k < 8; ++k) {
                double bv = v; int bi = tid;
                #pragma unroll
                for (int o = 32; o; o >>= 1) {
                    const double ov = __shfl_xor(bv, o, 64);
                    const int    oi = __shfl_xor(bi, o, 64);
                    if (ov > bv || (ov == bv && oi < bi)) { bv = ov; bi = oi; }
                }
                bw[k] = bv; ik[k] = bi;
                if (tid == bi) v = -1.0e300;
            }
            float wk[8]; float denom = 1e-20f;
            #pragma unroll
            for (int k = 0; k < 8; ++k) {
                wk[k] = __expf((float)bw[k] - m) * inv_s; denom += wk[k];
            }
            const float invd = 1.0f / denom;
            const size_t base = (size_t)tok * 8;
            const int oldtop = (int)outIdx[base];
            if (tid < 8) {
                outIdx[base + tid] = (float)ik[tid];
                outW[base + tid]   = wk[tid] * invd;
            }
            if (tid == 0 && ik[0] != oldtop) {
                atomicAdd(&wsf[NEXP + oldtop], -1.0f);
                atomicAdd(&wsf[NEXP + ik[0]],  1.0f);
            }
        }
        __syncthreads();
    }
}

__global__ void moe_final(const float* __restrict__ wsf, float* __restrict__ out) {
    const int e = threadIdx.x;  // 64 threads
    float v = wsf[e] * wsf[NEXP + e];
    #pragma unroll
    for (int o = 32; o; o >>= 1) v += __shfl_xor(v, o, 64);
    if (e == 0)
        out[2 * TOKS * 8] = v * (64.0f / ((float)TOKS * (float)TOKS));
}

// ===== fallback monolith (proven R2 path) for small ws =====
__global__ void moe_init(float* __restrict__ wsf, int n) {
    const int i = blockIdx.x * blockDim.x + threadIdx.x;
    if (i < n) wsf[i] = 0.0f;
}

__global__ void moe_w_cvt(const float* __restrict__ W, double* __restrict__ Wd) {
    const int i = blockIdx.x * blockDim.x + threadIdx.x;
    if (i < NEXP * HID) Wd[i] = (double)W[i];
}

__global__ __launch_bounds__(512, 2)
void moe_mono(const float* __restrict__ X, const double* __restrict__ Wd,
              float* __restrict__ out, float* __restrict__ wsf) {
    __shared__ double xs[64][66];
    __shared__ double L2[64][65];
    const int tid  = threadIdx.x;
    const int lane = tid & 63;
    const int wid  = __builtin_amdgcn_readfirstlane(tid >> 6);
    const int tok0 = blockIdx.x * 64;
    double acc[8] = {0., 0., 0., 0., 0., 0., 0., 0.};
    for (int h0 = 0; h0 < HID; h0 += 64) {
        #pragma unroll
        for (int i = 0; i < 8; ++i) {
            const int li = tid + i * 512;
            xs[li >> 6][li & 63] = (double)X[((size_t)(tok0 + (li >> 6)) << 12) + (h0 + (li & 63))];
        }
        __syncthreads();
        const double* wchunk = Wd + (((size_t)(wid << 3)) << 12) + h0;
        #pragma unroll 2
        for (int hh = 0; hh < 64; hh += 2) {
            const double2 xv = *(const double2*)&xs[lane][hh];
            #pragma unroll
            for (int e = 0; e < 8; ++e) {
                const double* wr = wchunk + (((size_t)e) << 12) + hh;
                acc[e] = fma(xv.x, wr[0], acc[e]);
                acc[e] = fma(xv.y, wr[1], acc[e]);
            }
        }
        __syncthreads();
    }
    #pragma unroll
    for (int e = 0; e < 8; ++e) L2[lane][(wid << 3) + e] = acc[e];
    __syncthreads();
    float* outIdx = out;
    float* outW   = out + (TOKS * 8);
    float rp = 0.0f;
    for (int tt = 0; tt < 8; ++tt) {
        const int t = (wid << 3) + tt;
        const double lg = L2[t][lane];
        const float lgf = (float)lg;
        float m = lgf;
        #pragma unroll
        for (int o = 32; o; o >>= 1) m = fmaxf(m, __shfl_xor(m, o, 64));
        const float p = __expf(lgf - m);
        float s = p;
        #pragma unroll
        for (int o = 32; o; o >>= 1) s += __shfl_xor(s, o, 64);
        const float inv_s = 1.0f / s;
        rp += p * inv_s;
        double v = lg;
        float wk[8]; int ik[8];
        #pragma unroll
        for (int k = 0; k < 8; ++k) {
            double bv = v; int bi = lane;
            #pragma unroll
            for (int o = 32; o; o >>= 1) {
                const double ov = __shfl_xor(bv, o, 64);
                const int    oi = __shfl_xor(bi, o, 64);
                if (ov > bv || (ov == bv && oi < bi)) { bv = ov; bi = oi; }
            }
            wk[k] = __expf((float)bv - m) * inv_s; ik[k] = bi;
            if (lane == bi) v = -1.0e300;
        }
        if (lane == 0) {
            const float denom = (((wk[0]+wk[1])+(wk[2]+wk[3])) +
                                 ((wk[4]+wk[5])+(wk[6]+wk[7]))) + 1e-20f;
            const float invd = 1.0f / denom;
            const size_t base = ((size_t)(tok0 + t)) << 3;
            #pragma unroll
            for (int k = 0; k < 8; ++k) {
                outIdx[base + k] = (float)ik[k];
                outW[base + k]   = wk[k] * invd;
            }
            atomicAdd(&wsf[NEXP + ik[0]], 1.0f);
        }
    }
    atomicAdd(&wsf[lane], rp);
}

extern "C" void kernel_launch(void* const* d_in, const int* in_sizes, int n_in,
                              void* d_out, int out_size, void* d_ws, size_t ws_size,
                              hipStream_t stream) {
    const float* X = (const float*)d_in[0];   // [4,4096,4096] fp32
    const float* W = (const float*)d_in[1];   // [64,4096] fp32
    float* out = (float*)d_out;
    float* wsf = (float*)d_ws;

    const size_t need = 4ull * WS_BPACK + 4ull * BPK_LO;  // slots + Bpack ~ 1.1 MB

    if (ws_size >= need) {
        unsigned short* Bpk = (unsigned short*)(wsf + WS_BPACK);
        moe_prep<<<(NEXP * HID + 255) / 256, 256, 0, stream>>>(W, Bpk, wsf);
        moe_fused<<<TOKS / 16, 512, 0, stream>>>(X, Bpk, out, wsf);
        moe_fix<<<256, 256, 0, stream>>>(X, W, out, wsf);
        moe_final<<<1, 64, 0, stream>>>(wsf, out);
    } else {
        double* Wd = (double*)d_ws;
        float* wsf2 = (float*)(Wd + NEXP * HID);
        moe_w_cvt<<<(NEXP * HID + 255) / 256, 256, 0, stream>>>(W, Wd);
        moe_init<<<1, 256, 0, stream>>>(wsf2, 128);
        moe_mono<<<TOKS / 64, 512, 0, stream>>>(X, Wd, out, wsf2);
        moe_final<<<1, 64, 0, stream>>>(wsf2, out);
    }
}

// Round 9
// 210.658 us; speedup vs baseline: 1.4422x; 1.4422x over previous
//
#include <hip/hip_runtime.h>
#include <hip/hip_bf16.h>

#define TOKS 16384
#define HID  4096
#define NEXP 64
#define EPS  1e-4f   // flag threshold; bf16-split logit err ~3e-6 -> 30x margin

// ===== ws layout (floats) =====
// [0..63] prob sums | [64..127] argmax counts | int@[128] flag count |
// ints [192..192+16384) flag list | [16576) Bpack (1 MB, bf16 hi/lo frag-packed)
#define WS_FLAGCNT  128
#define WS_FLAGLIST 192
#define WS_BPACK    16576
#define BPK_LO      262144   // ushort offset of lo plane inside Bpack

typedef __attribute__((ext_vector_type(8))) short short8_t;
typedef __attribute__((ext_vector_type(4))) float f32x4;

static __device__ __forceinline__ unsigned short f2bf_rn(float x) {
    unsigned u = __builtin_bit_cast(unsigned, x);
    u = (u + 0x7fffu + ((u >> 16) & 1u)) >> 16;
    return (unsigned short)u;
}
static __device__ __forceinline__ float bf2f(unsigned short h) {
    return __builtin_bit_cast(float, (unsigned)h << 16);
}

// ---------- prep: W -> frag-ready bf16 hi/lo pack; zero reduction slots ----------
// Bpack[kt 0..127][nt 0..3][lane 0..63][j 0..7] = Wsplit[n=nt*16+(lane&15)][k=kt*32+8*(lane>>4)+j]
__global__ void moe_prep(const float* __restrict__ W, unsigned short* __restrict__ Bpk,
                         float* __restrict__ wsf) {
    const int idx = blockIdx.x * blockDim.x + threadIdx.x;
    if (idx < 192) wsf[idx] = 0.0f;
    if (idx >= NEXP * HID) return;
    const int n = idx >> 12;
    const int k = idx & 4095;
    const float w = W[idx];
    const unsigned short hi = f2bf_rn(w);
    const unsigned short lo = f2bf_rn(w - bf2f(hi));
    const int kt   = k >> 5;
    const int nt   = n >> 4;
    const int lane = (n & 15) | (((k >> 3) & 3) << 4);
    const int j    = k & 7;
    const int dst  = (((kt << 2) + nt) << 9) + (lane << 3) + j;
    Bpk[dst]          = hi;
    Bpk[BPK_LO + dst] = lo;
}

// ---------- fused: register-direct MFMA GEMM + softmax + bitonic top-8 + flag ----------
// 512 thr = 8 waves; 32 tokens/block; wave w owns K-eighth (512 k = 16 kt steps) and
// BOTH 16-token tiles (mt=0,1) -> each B-fragment load feeds 6 MFMAs, halving B L2
// traffic vs R8, and acc/prefetch live in regs (launch_bounds caps VGPR at 128).
__global__ __launch_bounds__(512, 4)
void moe_fused(const float* __restrict__ X, const unsigned short* __restrict__ Bpk,
               float* __restrict__ out, float* __restrict__ wsf) {
    __shared__ __align__(16) float L[8][16][68];   // 34816 B, reused across 2 phases

    const int tid  = threadIdx.x;
    const int lane = tid & 63;
    const int w    = tid >> 6;            // K-eighth 0..7
    const int tok0 = blockIdx.x * 32;

    const int mrow = lane & 15;           // token row within 16-tile
    const int g    = lane >> 4;           // k-subgroup 0..3
    const size_t xoff0 = (size_t)(tok0 + mrow) * HID + ((size_t)w << 9) + (g << 3);
    const size_t xoff1 = xoff0 + (size_t)16 * HID;
    const unsigned short* bb0 = Bpk + (((size_t)w << 4) << 11) + (lane << 3);

    f32x4 acc[2][4];
    #pragma unroll
    for (int mt = 0; mt < 2; ++mt)
        #pragma unroll
        for (int nt = 0; nt < 4; ++nt) acc[mt][nt] = (f32x4){0.f, 0.f, 0.f, 0.f};

    float4 nxa0 = *(const float4*)&X[xoff0];
    float4 nxb0 = *(const float4*)&X[xoff0 + 4];
    float4 nxa1 = *(const float4*)&X[xoff1];
    float4 nxb1 = *(const float4*)&X[xoff1 + 4];

    #pragma unroll 4
    for (int c = 0; c < 16; ++c) {
        const float4 xa0 = nxa0, xb0 = nxb0, xa1 = nxa1, xb1 = nxb1;
        if (c < 15) {
            nxa0 = *(const float4*)&X[xoff0 + ((c + 1) << 5)];
            nxb0 = *(const float4*)&X[xoff0 + ((c + 1) << 5) + 4];
            nxa1 = *(const float4*)&X[xoff1 + ((c + 1) << 5)];
            nxb1 = *(const float4*)&X[xoff1 + ((c + 1) << 5) + 4];
        }
        short8_t ah[2], al[2];
        {
            const float xv0[8] = {xa0.x, xa0.y, xa0.z, xa0.w, xb0.x, xb0.y, xb0.z, xb0.w};
            const float xv1[8] = {xa1.x, xa1.y, xa1.z, xa1.w, xb1.x, xb1.y, xb1.z, xb1.w};
            #pragma unroll
            for (int j = 0; j < 8; ++j) {
                unsigned short hh = f2bf_rn(xv0[j]);
                ah[0][j] = (short)hh;
                al[0][j] = (short)f2bf_rn(xv0[j] - bf2f(hh));
                hh = f2bf_rn(xv1[j]);
                ah[1][j] = (short)hh;
                al[1][j] = (short)f2bf_rn(xv1[j] - bf2f(hh));
            }
        }
        const unsigned short* bb = bb0 + ((size_t)c << 11);
        #pragma unroll
        for (int nt = 0; nt < 4; ++nt) {
            const short8_t bh = *(const short8_t*)(bb + (nt << 9));
            const short8_t bl = *(const short8_t*)(bb + BPK_LO + (nt << 9));
            #pragma unroll
            for (int mt = 0; mt < 2; ++mt) {
                acc[mt][nt] = __builtin_amdgcn_mfma_f32_16x16x32_bf16(ah[mt], bh, acc[mt][nt], 0, 0, 0);
                acc[mt][nt] = __builtin_amdgcn_mfma_f32_16x16x32_bf16(al[mt], bh, acc[mt][nt], 0, 0, 0);
                acc[mt][nt] = __builtin_amdgcn_mfma_f32_16x16x32_bf16(ah[mt], bl, acc[mt][nt], 0, 0, 0);
            }
        }
    }

    // epilogue: 2 phases of 16 tokens; wave w reduces tokens w*2, w*2+1 per phase
    float* outIdx = out;
    float* outW   = out + TOKS * 8;
    int* flagcnt  = (int*)wsf + WS_FLAGCNT;
    int* flaglist = (int*)wsf + WS_FLAGLIST;

    float rp = 0.f;
    #pragma unroll
    for (int ph = 0; ph < 2; ++ph) {
        if (ph) __syncthreads();                    // protect L reuse
        #pragma unroll
        for (int nt = 0; nt < 4; ++nt)
            #pragma unroll
            for (int r = 0; r < 4; ++r)
                L[w][(g << 2) + r][(nt << 4) + mrow] = acc[ph][nt][r];
        __syncthreads();

        #pragma unroll
        for (int tt = 0; tt < 2; ++tt) {
            const int tl = (w << 1) + tt;
            const float lg = ((L[0][tl][lane] + L[1][tl][lane]) + (L[2][tl][lane] + L[3][tl][lane]))
                           + ((L[4][tl][lane] + L[5][tl][lane]) + (L[6][tl][lane] + L[7][tl][lane]));

            // bitonic sort-64, descending by (value, then lower index first)
            float v = lg; int idx = lane;
            #pragma unroll
            for (int size = 2; size <= 64; size <<= 1) {
                #pragma unroll
                for (int str = size >> 1; str > 0; str >>= 1) {
                    const float ov = __shfl_xor(v, str, 64);
                    const int   oi = __shfl_xor(idx, str, 64);
                    const bool pb = (ov > v) || (ov == v && oi < idx);  // partner ranks first
                    const bool keepFirst = ((lane & str) == 0) == ((lane & size) == 0);
                    if (pb == keepFirst) { v = ov; idx = oi; }
                }
            }

            const float m = __shfl(v, 0, 64);          // max logit
            const float p = __expf(lg - m);
            float s = p;
            #pragma unroll
            for (int o = 32; o; o >>= 1) s += __shfl_xor(s, o, 64);
            const float inv_s = 1.0f / s;
            rp += p * inv_s;

            const float wkv = __expf(v - m) * inv_s;   // my rank's score
            float d8 = (lane < 8) ? wkv : 0.f;
            #pragma unroll
            for (int o = 1; o < 8; o <<= 1) d8 += __shfl_xor(d8, o, 64);
            const float invd = 1.0f / (d8 + 1e-20f);
            const float nv = __shfl_down(v, 1, 64);
            const bool flg = __any(lane < 8 && (v - nv) < EPS);

            const int gtok = tok0 + (ph << 4) + tl;
            if (lane < 8) {
                outIdx[(size_t)gtok * 8 + lane] = (float)idx;
                outW[(size_t)gtok * 8 + lane]   = wkv * invd;
            }
            if (lane == 0) {
                atomicAdd(&wsf[NEXP + idx], 1.0f);     // argmax histogram
                if (flg) {
                    const int pos = atomicAdd(flagcnt, 1);
                    if (pos < TOKS) flaglist[pos] = gtok;
                }
            }
        }
    }
    atomicAdd(&wsf[lane], rp);
}

// ---------- exact fp64 redo for flagged tokens ----------
__global__ __launch_bounds__(256, 2)
void moe_fix(const float* __restrict__ X, const float* __restrict__ W,
             float* __restrict__ out, float* __restrict__ wsf) {
    __shared__ double red[256];
    const int tid = threadIdx.x;
    const int e   = tid & 63;
    const int kc  = tid >> 6;
    const int nf  = min(*((int*)wsf + WS_FLAGCNT), TOKS);
    const int* flaglist = (const int*)wsf + WS_FLAGLIST;
    float* outIdx = out;
    float* outW   = out + TOKS * 8;

    for (int fi = blockIdx.x; fi < nf; fi += gridDim.x) {
        const int tok = flaglist[fi];
        const float* xrow = X + (size_t)tok * HID + kc * 1024;
        const float* wrow = W + (size_t)e  * HID + kc * 1024;
        double part = 0.0;
        for (int j = 0; j < 1024; j += 4) {
            const float4 xv = *(const float4*)(xrow + j);
            const float4 wv = *(const float4*)(wrow + j);
            part = fma((double)xv.x, (double)wv.x, part);
            part = fma((double)xv.y, (double)wv.y, part);
            part = fma((double)xv.z, (double)wv.z, part);
            part = fma((double)xv.w, (double)wv.w, part);
        }
        red[tid] = part;
        __syncthreads();
        if (tid < 64) {
            const double lg = ((red[tid] + red[64 + tid]) + red[128 + tid]) + red[192 + tid];
            const float lgf = (float)lg;
            float m = lgf;
            #pragma unroll
            for (int o = 32; o; o >>= 1) m = fmaxf(m, __shfl_xor(m, o, 64));
            const float p = __expf(lgf - m);
            float s = p;
            #pragma unroll
            for (int o = 32; o; o >>= 1) s += __shfl_xor(s, o, 64);
            const float inv_s = 1.0f / s;

            double v = lg;
            double bw[8]; int ik[8];
            #pragma unroll
            for (int k = 0; k < 8; ++k) {
                double bv = v; int bi = tid;
                #pragma unroll
                for (int o = 32; o; o >>= 1) {
                    const double ov = __shfl_xor(bv, o, 64);
                    const int    oi = __shfl_xor(bi, o, 64);
                    if (ov > bv || (ov == bv && oi < bi)) { bv = ov; bi = oi; }
                }
                bw[k] = bv; ik[k] = bi;
                if (tid == bi) v = -1.0e300;
            }
            float wk[8]; float denom = 1e-20f;
            #pragma unroll
            for (int k = 0; k < 8; ++k) {
                wk[k] = __expf((float)bw[k] - m) * inv_s; denom += wk[k];
            }
            const float invd = 1.0f / denom;
            const size_t base = (size_t)tok * 8;
            const int oldtop = (int)outIdx[base];
            if (tid < 8) {
                outIdx[base + tid] = (float)ik[tid];
                outW[base + tid]   = wk[tid] * invd;
            }
            if (tid == 0 && ik[0] != oldtop) {
                atomicAdd(&wsf[NEXP + oldtop], -1.0f);
                atomicAdd(&wsf[NEXP + ik[0]],  1.0f);
            }
        }
        __syncthreads();
    }
}

__global__ void moe_final(const float* __restrict__ wsf, float* __restrict__ out) {
    const int e = threadIdx.x;  // 64 threads
    float v = wsf[e] * wsf[NEXP + e];
    #pragma unroll
    for (int o = 32; o; o >>= 1) v += __shfl_xor(v, o, 64);
    if (e == 0)
        out[2 * TOKS * 8] = v * (64.0f / ((float)TOKS * (float)TOKS));
}

// ===== fallback monolith (proven R2 path) for small ws =====
__global__ void moe_init(float* __restrict__ wsf, int n) {
    const int i = blockIdx.x * blockDim.x + threadIdx.x;
    if (i < n) wsf[i] = 0.0f;
}

__global__ void moe_w_cvt(const float* __restrict__ W, double* __restrict__ Wd) {
    const int i = blockIdx.x * blockDim.x + threadIdx.x;
    if (i < NEXP * HID) Wd[i] = (double)W[i];
}

__global__ __launch_bounds__(512, 2)
void moe_mono(const float* __restrict__ X, const double* __restrict__ Wd,
              float* __restrict__ out, float* __restrict__ wsf) {
    __shared__ double xs[64][66];
    __shared__ double L2[64][65];
    const int tid  = threadIdx.x;
    const int lane = tid & 63;
    const int wid  = __builtin_amdgcn_readfirstlane(tid >> 6);
    const int tok0 = blockIdx.x * 64;
    double acc[8] = {0., 0., 0., 0., 0., 0., 0., 0.};
    for (int h0 = 0; h0 < HID; h0 += 64) {
        #pragma unroll
        for (int i = 0; i < 8; ++i) {
            const int li = tid + i * 512;
            xs[li >> 6][li & 63] = (double)X[((size_t)(tok0 + (li >> 6)) << 12) + (h0 + (li & 63))];
        }
        __syncthreads();
        const double* wchunk = Wd + (((size_t)(wid << 3)) << 12) + h0;
        #pragma unroll 2
        for (int hh = 0; hh < 64; hh += 2) {
            const double2 xv = *(const double2*)&xs[lane][hh];
            #pragma unroll
            for (int e = 0; e < 8; ++e) {
                const double* wr = wchunk + (((size_t)e) << 12) + hh;
                acc[e] = fma(xv.x, wr[0], acc[e]);
                acc[e] = fma(xv.y, wr[1], acc[e]);
            }
        }
        __syncthreads();
    }
    #pragma unroll
    for (int e = 0; e < 8; ++e) L2[lane][(wid << 3) + e] = acc[e];
    __syncthreads();
    float* outIdx = out;
    float* outW   = out + (TOKS * 8);
    float rp = 0.0f;
    for (int tt = 0; tt < 8; ++tt) {
        const int t = (wid << 3) + tt;
        const double lg = L2[t][lane];
        const float lgf = (float)lg;
        float m = lgf;
        #pragma unroll
        for (int o = 32; o; o >>= 1) m = fmaxf(m, __shfl_xor(m, o, 64));
        const float p = __expf(lgf - m);
        float s = p;
        #pragma unroll
        for (int o = 32; o; o >>= 1) s += __shfl_xor(s, o, 64);
        const float inv_s = 1.0f / s;
        rp += p * inv_s;
        double v = lg;
        float wk[8]; int ik[8];
        #pragma unroll
        for (int k = 0; k < 8; ++k) {
            double bv = v; int bi = lane;
            #pragma unroll
            for (int o = 32; o; o >>= 1) {
                const double ov = __shfl_xor(bv, o, 64);
                const int    oi = __shfl_xor(bi, o, 64);
                if (ov > bv || (ov == bv && oi < bi)) { bv = ov; bi = oi; }
            }
            wk[k] = __expf((float)bv - m) * inv_s; ik[k] = bi;
            if (lane == bi) v = -1.0e300;
        }
        if (lane == 0) {
            const float denom = (((wk[0]+wk[1])+(wk[2]+wk[3])) +
                                 ((wk[4]+wk[5])+(wk[6]+wk[7]))) + 1e-20f;
            const float invd = 1.0f / denom;
            const size_t base = ((size_t)(tok0 + t)) << 3;
            #pragma unroll
            for (int k = 0; k < 8; ++k) {
                outIdx[base + k] = (float)ik[k];
                outW[base + k]   = wk[k] * invd;
            }
            atomicAdd(&wsf[NEXP + ik[0]], 1.0f);
        }
    }
    atomicAdd(&wsf[lane], rp);
}

extern "C" void kernel_launch(void* const* d_in, const int* in_sizes, int n_in,
                              void* d_out, int out_size, void* d_ws, size_t ws_size,
                              hipStream_t stream) {
    const float* X = (const float*)d_in[0];   // [4,4096,4096] fp32
    const float* W = (const float*)d_in[1];   // [64,4096] fp32
    float* out = (float*)d_out;
    float* wsf = (float*)d_ws;

    const size_t need = 4ull * WS_BPACK + 4ull * BPK_LO;  // slots + Bpack ~ 1.1 MB

    if (ws_size >= need) {
        unsigned short* Bpk = (unsigned short*)(wsf + WS_BPACK);
        moe_prep<<<(NEXP * HID + 255) / 256, 256, 0, stream>>>(W, Bpk, wsf);
        moe_fused<<<TOKS / 32, 512, 0, stream>>>(X, Bpk, out, wsf);
        moe_fix<<<256, 256, 0, stream>>>(X, W, out, wsf);
        moe_final<<<1, 64, 0, stream>>>(wsf, out);
    } else {
        double* Wd = (double*)d_ws;
        float* wsf2 = (float*)(Wd + NEXP * HID);
        moe_w_cvt<<<(NEXP * HID + 255) / 256, 256, 0, stream>>>(W, Wd);
        moe_init<<<1, 256, 0, stream>>>(wsf2, 128);
        moe_mono<<<TOKS / 64, 512, 0, stream>>>(X, Wd, out, wsf2);
        moe_final<<<1, 64, 0, stream>>>(wsf2, out);
    }
}